// Round 2
// baseline (449.150 us; speedup 1.0000x reference)
//
#include <hip/hip_runtime.h>
#include <stdint.h>

// UnarySqrt scan, T=64 steps, N=2^20 channels, exact {0,1} floats.
//   per step: p = x*(1-tr); out = tr + p; tr' = p
// On {0,1} data this is 1-bit logic: out = tr|x ; tr' = x & ~tr.
//
// R16: fill-clone expand.
// R15 result: phase separation (pack 256MB-read -> 8MB ws; expand -> 256MB
// write) gained only 10.5 us. Each pure phase runs ~3.3-3.5 TB/s while the
// harness's pure-write fill sustains 6.5 TB/s in the same graph. So the wall
// tracks KERNEL STRUCTURE, not stream mix. Difference: fill = tiny blocks,
// 1 elem/thread/step, huge grid, contiguous per-block ranges; ours = 256 fat
// blocks, per-thread 64-row column walk at 4MB stride.
// Expand has no scan dependency -> clone the fill exactly:
//   16384 blocks x 256 thr, each block owns 1024 consecutive v4f (16 KB) of
//   out at a single scalar t; bits come from the 8 MB ws (L3-resident after
//   pack's writeback -> ~0 HBM fetch).
// Predicted: expand ~77 -> ~45 us, dur_us 425 -> ~390. If unchanged, pack is
// the slow phase -> next round parallelize the scan in t (transfer function
// of tr'=x&~tr composes to {const0,const1,id,not} = 2-bit state).

typedef float v4f __attribute__((ext_vector_type(4)));
typedef uint32_t v4u __attribute__((ext_vector_type(4)));

// ---------------------------------------------------------------- phase 1
// Pure-read pass: scan + pack. ws_lo[idx] = bits t=0..31 of the 4 columns
// in v4f-group idx; ws_hi[idx] = bits t=32..63. Plain loads (restore may
// leave input L3-resident; hints measured inert in R14/R15 anyway).
__global__ __launch_bounds__(1024) void UnarySqrt_pack(
    const v4f* __restrict__ in,      // [64, stride]
    const v4f* __restrict__ trace0,  // [stride]
    v4u* __restrict__ ws_lo,         // [stride]
    v4u* __restrict__ ws_hi,         // [stride]
    int stride)
{
    const int idx = blockIdx.x * blockDim.x + threadIdx.x;
    if (idx >= stride) return;

    v4f t0 = trace0[idx];
    uint32_t tr[4];
    #pragma unroll
    for (int j = 0; j < 4; ++j) tr[j] = (t0[j] != 0.0f) ? 1u : 0u;

    v4u lo = {0u, 0u, 0u, 0u};
    #pragma unroll 8
    for (int t = 0; t < 32; ++t) {
        v4f x = in[(size_t)t * (size_t)stride + (size_t)idx];
        #pragma unroll
        for (int j = 0; j < 4; ++j) {
            uint32_t xb = (x[j] != 0.0f) ? 1u : 0u;
            lo[j] |= (xb | tr[j]) << t;      // out bit
            tr[j] = xb & (tr[j] ^ 1u);       // JKFF: J=out, K=1
        }
    }
    v4u hi = {0u, 0u, 0u, 0u};
    #pragma unroll 8
    for (int t = 32; t < 64; ++t) {
        v4f x = in[(size_t)t * (size_t)stride + (size_t)idx];
        #pragma unroll
        for (int j = 0; j < 4; ++j) {
            uint32_t xb = (x[j] != 0.0f) ? 1u : 0u;
            hi[j] |= (xb | tr[j]) << (t - 32);
            tr[j] = xb & (tr[j] ^ 1u);
        }
    }
    ws_lo[idx] = lo;   // 8 MB total; dirty L2 -> flushed to L3 at kernel end
    ws_hi[idx] = hi;
}

// ---------------------------------------------------------------- phase 2
// Fill-clone pure-write pass. Each block: 1024 consecutive v4f (16 KB) of
// out, all at one scalar t (stride%1024==0 guarantees no straddle). Reads
// 16 KB of packed words from L3-resident ws, expands bit t.
__global__ __launch_bounds__(256) void UnarySqrt_expand_flat(
    const v4u* __restrict__ ws_lo,
    const v4u* __restrict__ ws_hi,
    v4f* __restrict__ out,           // [64, stride]
    int stride)
{
    const size_t base = (size_t)blockIdx.x * 1024;
    const int t = (int)(base / (size_t)stride);       // scalar per block
    const int bit = t & 31;
    const v4u* __restrict__ half = (t < 32) ? ws_lo : ws_hi;
    const int idx0 = (int)(base % (size_t)stride);

    #pragma unroll
    for (int k = 0; k < 4; ++k) {
        const int idx = idx0 + k * 256 + (int)threadIdx.x;
        v4u w = half[idx];
        v4f o;
        #pragma unroll
        for (int j = 0; j < 4; ++j)
            o[j] = (float)((w[j] >> bit) & 1u);
        out[base + (size_t)(k * 256) + threadIdx.x] = o;
    }
}

// -------------------------------------------------- fallback: single pass
// (R14 best structure — correct for T==64 without workspace.)
__global__ __launch_bounds__(1024) void UnarySqrt_kernel(
    const v4f* __restrict__ in, const v4f* __restrict__ trace0,
    v4f* __restrict__ out, int stride)
{
    const int idx = blockIdx.x * blockDim.x + threadIdx.x;
    if (idx >= stride) return;

    v4f tr = trace0[idx];
    v4f x  = __builtin_nontemporal_load(&in[idx]);

    #pragma unroll 8
    for (int t = 0; t < 64; ++t) {
        v4f xn;
        if (t + 1 < 64) {
            xn = __builtin_nontemporal_load(
                &in[(size_t)(t + 1) * (size_t)stride + (size_t)idx]);
        }
        v4f p = x * (1.0f - tr);
        v4f o = tr + p;
        out[(size_t)t * (size_t)stride + (size_t)idx] = o;
        tr = p;
        x = xn;
    }
}

// Generic fallback (correct for any T, N%4==0, arbitrary float inputs).
__global__ __launch_bounds__(256) void UnarySqrt_generic(
    const v4f* __restrict__ in, const v4f* __restrict__ trace0,
    v4f* __restrict__ out, int stride, int T)
{
    int idx = blockIdx.x * blockDim.x + threadIdx.x;
    if (idx >= stride) return;
    v4f tr = trace0[idx];
    for (int t = 0; t < T; ++t) {
        v4f x = in[(size_t)t * stride + idx];
        v4f p = x * (1.0f - tr);
        out[(size_t)t * stride + idx] = tr + p;
        tr = p;
    }
}

extern "C" void kernel_launch(void* const* d_in, const int* in_sizes, int n_in,
                              void* d_out, int out_size, void* d_ws, size_t ws_size,
                              hipStream_t stream) {
    const float* bits   = (const float*)d_in[0];  // [T, N]
    const float* trace0 = (const float*)d_in[1];  // [N]

    int N = in_sizes[1];
    int T = in_sizes[0] / N;
    int stride = N / 4;

    size_t ws_needed = (size_t)stride * 2 * sizeof(v4u);  // 8 MB at N=2^20

    if (T == 64 && (stride % 1024) == 0 && d_ws && ws_size >= ws_needed) {
        v4u* ws_lo = (v4u*)d_ws;
        v4u* ws_hi = ws_lo + stride;

        int pack_grid = stride / 1024;           // 256 blocks @ N=2^20
        UnarySqrt_pack<<<pack_grid, 1024, 0, stream>>>(
            (const v4f*)bits, (const v4f*)trace0, ws_lo, ws_hi, stride);

        size_t M = (size_t)T * (size_t)stride;   // total v4f elements of out
        int exp_grid = (int)(M / 1024);          // 16384 blocks @ N=2^20
        UnarySqrt_expand_flat<<<exp_grid, 256, 0, stream>>>(
            ws_lo, ws_hi, (v4f*)d_out, stride);
    } else if (T == 64 && (stride % 1024) == 0) {
        int grid = stride / 1024;
        UnarySqrt_kernel<<<grid, 1024, 0, stream>>>(
            (const v4f*)bits, (const v4f*)trace0, (v4f*)d_out, stride);
    } else {
        int block = 256;
        int grid = (stride + block - 1) / block;
        UnarySqrt_generic<<<grid, block, 0, stream>>>(
            (const v4f*)bits, (const v4f*)trace0, (v4f*)d_out, stride, T);
    }
}

// Round 3
// 443.544 us; speedup vs baseline: 1.0126x; 1.0126x over previous
//
#include <hip/hip_runtime.h>
#include <stdint.h>

// UnarySqrt scan, T=64 steps, N=2^20 channels, exact {0,1} floats.
//   per step: p = x*(1-tr); out = tr + p; tr' = p
// On {0,1} data this is 1-bit logic: out = tr|x ; tr' = x & ~tr.
//
// R17: t-parallel affine scan (fused, 4-way t-split).
// R15: stream separation inert (+10 us). R16: fill-clone expand REGRESSED
// (+24 us) -- 32x ws read amplification; L3 reads are not free. Remaining
// untried axis: every R1..R16 variant runs a SERIAL per-thread scan over
// >=32 rows (16 waves/CU, long dep chains). The recurrence tr' = x & ~tr
// is affine over GF(2):  tr = a ^ (b & T0)  =>  a' = x&~a, b' = x&b.
// So each thread scans a 16-step t-chunk blind, producing packed out-words
// for BOTH possible incoming traces (o0, o1) plus the (a,b) transfer
// function; one LDS exchange + <=3-step fixup chains the 4 chunks.
//   - 1M threads (4x), 4096 blocks x 256, tiny LDS, low VGPR -> up to
//     32 waves/CU (vs 16 before), 4x shorter dependency chains
//   - single kernel: no ws round-trip, no second dispatch
// Predicted: kernel ~160 -> ~90-105 us, dur 449 -> ~360-380. If it lands
// back at ~425+, the ~3.3 TB/s mixed rate is structure-independent and the
// remainder is harness-fixed => roofline.

typedef float v4f __attribute__((ext_vector_type(4)));

#define SPLIT 4      // t-chunks per column
#define CHUNK 16     // 64 / SPLIT
#define COLS  64     // v4f column-groups per block (block = COLS*SPLIT = 256 thr)

__global__ __launch_bounds__(256) void UnarySqrt_tsplit(
    const v4f* __restrict__ in,      // [64, stride]
    const v4f* __restrict__ trace0,  // [stride]
    v4f* __restrict__ out,           // [64, stride]
    int stride)
{
    __shared__ uint32_t ab[SPLIT][COLS];  // per chunk/col: a (bits 0..3), b (bits 4..7)

    const int c = threadIdx.x & (COLS - 1);   // column within block
    const int s = threadIdx.x >> 6;           // t-chunk 0..3 (lanes of a wave share s)
    const int idx = blockIdx.x * COLS + c;    // v4f column-group
    const int tbase = s * CHUNK;

    // Blind affine scan of rows tbase..tbase+15.
    // Per channel j: tr = a_j ^ (b_j & T0);  a' = x&~a, b' = x&b.
    uint32_t a = 0u, b = 0xFu;                // 4 channels packed in nibbles
    uint32_t o0[4] = {0u, 0u, 0u, 0u};        // packed out bits if T0=0
    uint32_t o1[4] = {0u, 0u, 0u, 0u};        // packed out bits if T0=1
    #pragma unroll 4
    for (int u = 0; u < CHUNK; ++u) {
        v4f x = in[(size_t)(tbase + u) * (size_t)stride + (size_t)idx];
        #pragma unroll
        for (int j = 0; j < 4; ++j) {
            uint32_t xb = (x[j] != 0.0f) ? 1u : 0u;
            uint32_t aj = (a >> j) & 1u;
            uint32_t bj = (b >> j) & 1u;
            o0[j] |= (xb | aj) << u;                 // out = x | tr  (T0=0)
            o1[j] |= (xb | (aj ^ bj)) << u;          //               (T0=1)
            uint32_t an = xb & (aj ^ 1u);            // a' = x & ~a
            uint32_t bn = xb & bj;                   // b' = x & b
            a = (a & ~(1u << j)) | (an << j);
            b = (b & ~(1u << j)) | (bn << j);
        }
    }
    ab[s][c] = a | (b << 4);
    __syncthreads();

    // Resolve this chunk's actual incoming trace per channel.
    v4f t0v = trace0[idx];
    uint32_t T[4];
    #pragma unroll
    for (int j = 0; j < 4; ++j) T[j] = (t0v[j] != 0.0f) ? 1u : 0u;
    for (int ss = 0; ss < s; ++ss) {          // <=3 serial steps
        uint32_t w = ab[ss][c];
        #pragma unroll
        for (int j = 0; j < 4; ++j) {
            uint32_t A = (w >> j) & 1u;
            uint32_t B = (w >> (4 + j)) & 1u;
            T[j] = A ^ (B & T[j]);
        }
    }

    // Select and expand.
    uint32_t sel[4];
    #pragma unroll
    for (int j = 0; j < 4; ++j) sel[j] = T[j] ? o1[j] : o0[j];

    #pragma unroll 4
    for (int u = 0; u < CHUNK; ++u) {
        v4f o;
        #pragma unroll
        for (int j = 0; j < 4; ++j)
            o[j] = (float)((sel[j] >> u) & 1u);
        out[(size_t)(tbase + u) * (size_t)stride + (size_t)idx] = o;
    }
}

// -------------------------------------------------- fallback: single pass
// (R14 best structure — correct for T==64 without workspace.)
__global__ __launch_bounds__(1024) void UnarySqrt_kernel(
    const v4f* __restrict__ in, const v4f* __restrict__ trace0,
    v4f* __restrict__ out, int stride)
{
    const int idx = blockIdx.x * blockDim.x + threadIdx.x;
    if (idx >= stride) return;

    v4f tr = trace0[idx];
    v4f x  = __builtin_nontemporal_load(&in[idx]);

    #pragma unroll 8
    for (int t = 0; t < 64; ++t) {
        v4f xn;
        if (t + 1 < 64) {
            xn = __builtin_nontemporal_load(
                &in[(size_t)(t + 1) * (size_t)stride + (size_t)idx]);
        }
        v4f p = x * (1.0f - tr);
        v4f o = tr + p;
        out[(size_t)t * (size_t)stride + (size_t)idx] = o;
        tr = p;
        x = xn;
    }
}

// Generic fallback (correct for any T, N%4==0, arbitrary float inputs).
__global__ __launch_bounds__(256) void UnarySqrt_generic(
    const v4f* __restrict__ in, const v4f* __restrict__ trace0,
    v4f* __restrict__ out, int stride, int T)
{
    int idx = blockIdx.x * blockDim.x + threadIdx.x;
    if (idx >= stride) return;
    v4f tr = trace0[idx];
    for (int t = 0; t < T; ++t) {
        v4f x = in[(size_t)t * stride + idx];
        v4f p = x * (1.0f - tr);
        out[(size_t)t * stride + idx] = tr + p;
        tr = p;
    }
}

extern "C" void kernel_launch(void* const* d_in, const int* in_sizes, int n_in,
                              void* d_out, int out_size, void* d_ws, size_t ws_size,
                              hipStream_t stream) {
    const float* bits   = (const float*)d_in[0];  // [T, N]
    const float* trace0 = (const float*)d_in[1];  // [N]

    int N = in_sizes[1];
    int T = in_sizes[0] / N;
    int stride = N / 4;

    if (T == 64 && (stride % COLS) == 0) {
        int grid = stride / COLS;                 // 4096 blocks @ N=2^20
        UnarySqrt_tsplit<<<grid, COLS * SPLIT, 0, stream>>>(
            (const v4f*)bits, (const v4f*)trace0, (v4f*)d_out, stride);
    } else if (T == 64 && (stride % 1024) == 0) {
        int grid = stride / 1024;
        UnarySqrt_kernel<<<grid, 1024, 0, stream>>>(
            (const v4f*)bits, (const v4f*)trace0, (v4f*)d_out, stride);
    } else {
        int block = 256;
        int grid = (stride + block - 1) / block;
        UnarySqrt_generic<<<grid, block, 0, stream>>>(
            (const v4f*)bits, (const v4f*)trace0, (v4f*)d_out, stride, T);
    }
}